// Round 1
// baseline (149.610 us; speedup 1.0000x reference)
//
#include <hip/hip_runtime.h>

#define D  16
#define NB 262144
#define NG 20000

// ---------------------------------------------------------------------------
// Kernel 1: build M[n,k,j] = sum_m BD[n,m] * BW[n,m,k] * BW[m,n,j]
// stored as Mt[(k*16+j)*16 + n] for the main kernel's access pattern.
// 256 threads, one (k,j) pair per thread.
// ---------------------------------------------------------------------------
__global__ void build_M_kernel(const float* __restrict__ BW,
                               const float* __restrict__ BD,
                               float* __restrict__ Mt) {
    int kj = threadIdx.x;          // 0..255
    int k = kj >> 4;
    int j = kj & 15;
    #pragma unroll
    for (int n = 0; n < D; ++n) {
        float acc = 0.f;
        #pragma unroll
        for (int m = 0; m < D; ++m) {
            acc += BD[n * D + m] * BW[(n * D + m) * D + k] * BW[(m * D + n) * D + j];
        }
        Mt[kj * D + n] = acc;
    }
}

// ---------------------------------------------------------------------------
// Kernel 2: per-gene MLP table  T[g] = W3*relu(W2*relu(W1*emb[g]+b1)+b2)+b3
// One thread per gene; weights are wave-uniform -> scalar loads.
// ---------------------------------------------------------------------------
__global__ void gene_mlp_kernel(const float* __restrict__ emb,
                                const float* __restrict__ W1, const float* __restrict__ b1,
                                const float* __restrict__ W2, const float* __restrict__ b2,
                                const float* __restrict__ W3, const float* __restrict__ b3,
                                float* __restrict__ T) {
    int g = blockIdx.x * blockDim.x + threadIdx.x;
    if (g >= NG) return;

    float h[D], t[D];
    const float4* ep = (const float4*)(emb + (size_t)g * D);
    float4 v0 = ep[0], v1 = ep[1], v2 = ep[2], v3 = ep[3];
    h[0]=v0.x; h[1]=v0.y; h[2]=v0.z; h[3]=v0.w;
    h[4]=v1.x; h[5]=v1.y; h[6]=v1.z; h[7]=v1.w;
    h[8]=v2.x; h[9]=v2.y; h[10]=v2.z; h[11]=v2.w;
    h[12]=v3.x; h[13]=v3.y; h[14]=v3.z; h[15]=v3.w;

    #pragma unroll
    for (int i = 0; i < D; ++i) {
        float a = b1[i];
        #pragma unroll
        for (int d = 0; d < D; ++d) a = fmaf(W1[i * D + d], h[d], a);
        t[i] = fmaxf(a, 0.f);
    }
    #pragma unroll
    for (int i = 0; i < D; ++i) {
        float a = b2[i];
        #pragma unroll
        for (int d = 0; d < D; ++d) a = fmaf(W2[i * D + d], t[d], a);
        h[i] = fmaxf(a, 0.f);
    }
    #pragma unroll
    for (int i = 0; i < D; ++i) {
        float a = b3[i];
        #pragma unroll
        for (int d = 0; d < D; ++d) a = fmaf(W3[i * D + d], h[d], a);
        t[i] = a;
    }

    float4* tp = (float4*)(T + (size_t)g * D);
    tp[0] = make_float4(t[0], t[1], t[2], t[3]);
    tp[1] = make_float4(t[4], t[5], t[6], t[7]);
    tp[2] = make_float4(t[8], t[9], t[10], t[11]);
    tp[3] = make_float4(t[12], t[13], t[14], t[15]);
}

// ---------------------------------------------------------------------------
// Kernel 3: per-row main compute.
//   e0 = T[x[b,0]], e1 = T[x[b,1]]
//   z[n] = Boff[n] + sum_{k,j} e0[k]*e1[j]*Mt[(k*16+j)*16+n]
//   u[i] = relu(sum_n Wc1[i,n]*z[n] + bc1[i])
//   out[b] = phenos[b,0]+phenos[b,1] + sum_i Wc2[i]*u[i] + bc2
// Mt / Boff / Wc1 / bc1 / Wc2 / bc2 are uniform -> scalar loads.
// ---------------------------------------------------------------------------
__global__ void __launch_bounds__(256)
main_kernel(const int* __restrict__ x, const float* __restrict__ phenos,
            const float* __restrict__ T, const float* __restrict__ Mt,
            const float* __restrict__ Boff, const float* __restrict__ Wc1,
            const float* __restrict__ bc1, const float* __restrict__ Wc2,
            const float* __restrict__ bc2, float* __restrict__ out) {
    int b = blockIdx.x * blockDim.x + threadIdx.x;
    if (b >= NB) return;

    int g0 = x[2 * b];
    int g1 = x[2 * b + 1];

    float e0[D], e1[D];
    {
        const float4* p0 = (const float4*)(T + (size_t)g0 * D);
        const float4* p1 = (const float4*)(T + (size_t)g1 * D);
        float4 a0 = p0[0], a1 = p0[1], a2 = p0[2], a3 = p0[3];
        float4 c0 = p1[0], c1 = p1[1], c2 = p1[2], c3 = p1[3];
        e0[0]=a0.x; e0[1]=a0.y; e0[2]=a0.z; e0[3]=a0.w;
        e0[4]=a1.x; e0[5]=a1.y; e0[6]=a1.z; e0[7]=a1.w;
        e0[8]=a2.x; e0[9]=a2.y; e0[10]=a2.z; e0[11]=a2.w;
        e0[12]=a3.x; e0[13]=a3.y; e0[14]=a3.z; e0[15]=a3.w;
        e1[0]=c0.x; e1[1]=c0.y; e1[2]=c0.z; e1[3]=c0.w;
        e1[4]=c1.x; e1[5]=c1.y; e1[6]=c1.z; e1[7]=c1.w;
        e1[8]=c2.x; e1[9]=c2.y; e1[10]=c2.z; e1[11]=c2.w;
        e1[12]=c3.x; e1[13]=c3.y; e1[14]=c3.z; e1[15]=c3.w;
    }

    float z[D];
    #pragma unroll
    for (int n = 0; n < D; ++n) z[n] = Boff[n];

    // z[n] += sum_{k,j} e0[k]*e1[j]*Mt[(k,j),n]
    for (int k = 0; k < D; ++k) {
        float a = e0[k];
        #pragma unroll
        for (int j = 0; j < D; ++j) {
            float p = a * e1[j];
            const float* m = Mt + ((k * D + j) * D);
            #pragma unroll
            for (int n = 0; n < D; ++n) {
                z[n] = fmaf(p, m[n], z[n]);
            }
        }
    }

    // classifier head
    float acc = bc2[0];
    #pragma unroll
    for (int i = 0; i < D; ++i) {
        float u = bc1[i];
        #pragma unroll
        for (int n = 0; n < D; ++n) u = fmaf(Wc1[i * D + n], z[n], u);
        u = fmaxf(u, 0.f);
        acc = fmaf(Wc2[i], u, acc);
    }

    out[b] = phenos[2 * b] + phenos[2 * b + 1] + acc;
}

// ---------------------------------------------------------------------------
extern "C" void kernel_launch(void* const* d_in, const int* in_sizes, int n_in,
                              void* d_out, int out_size, void* d_ws, size_t ws_size,
                              hipStream_t stream) {
    const int*   x      = (const int*)  d_in[0];
    const float* phenos = (const float*)d_in[1];
    const float* emb    = (const float*)d_in[2];
    const float* W1     = (const float*)d_in[3];
    const float* b1     = (const float*)d_in[4];
    const float* W2     = (const float*)d_in[5];
    const float* b2     = (const float*)d_in[6];
    const float* W3     = (const float*)d_in[7];
    const float* b3     = (const float*)d_in[8];
    const float* BW     = (const float*)d_in[9];
    const float* BD     = (const float*)d_in[10];
    const float* Boff   = (const float*)d_in[11];
    const float* Wc1    = (const float*)d_in[12];
    const float* bc1    = (const float*)d_in[13];
    const float* Wc2    = (const float*)d_in[14];
    const float* bc2    = (const float*)d_in[15];
    float* out = (float*)d_out;

    // workspace layout: Mt (4096 f32 = 16 KB) | T (320000 f32 = 1.25 MB)
    float* Mt = (float*)d_ws;
    float* T  = (float*)d_ws + 4096;

    build_M_kernel<<<1, 256, 0, stream>>>(BW, BD, Mt);
    gene_mlp_kernel<<<(NG + 255) / 256, 256, 0, stream>>>(emb, W1, b1, W2, b2, W3, b3, T);
    main_kernel<<<NB / 256, 256, 0, stream>>>(x, phenos, T, Mt, Boff, Wc1, bc1, Wc2, bc2, out);
}

// Round 2
// 126.733 us; speedup vs baseline: 1.1805x; 1.1805x over previous
//
#include <hip/hip_runtime.h>

#define D  16
#define NB 262144
#define NG 20000

typedef __attribute__((ext_vector_type(8))) short bf16x8;
typedef __attribute__((ext_vector_type(4))) float f32x4;

// pack the high 16 bits (bf16-truncation) of two f32s into one dword:
// low half = hi16(b0), high half = hi16(b1)
__device__ __forceinline__ unsigned pack_hi16(unsigned b0, unsigned b1) {
    return __builtin_amdgcn_perm(b1, b0, 0x07060302u);
}

// ---------------------------------------------------------------------------
// Build kernel: M[n,k,j] = sum_m BD[n,m]*BW[n,m,k]*BW[m,n,j], then repack as
// bf16 hi/lo B-operand fragments for mfma_f32_16x16x32_bf16:
//   B[kk][n], kk=k*16+j (K=256, 8 slices of 32), lane n=lane&15, k-chunk by quad.
//   Bhi/Blo[idx = s*64+lane] = 8 bf16 (one dwordx4).
// Also folds Boff into bc1: bc1p[i] = bc1[i] + sum_n Wc1[i,n]*Boff[n].
// ---------------------------------------------------------------------------
__global__ void build_kernel(const float* __restrict__ BW, const float* __restrict__ BD,
                             const float* __restrict__ Wc1, const float* __restrict__ bc1,
                             const float* __restrict__ Boff,
                             short* __restrict__ Bhi, short* __restrict__ Blo,
                             float* __restrict__ bc1p) {
    __shared__ float bw[4096];
    __shared__ float bd[256];
    __shared__ float M[256][16];
    int tid = threadIdx.x;
    #pragma unroll
    for (int i = 0; i < 16; ++i) bw[tid + 256 * i] = BW[tid + 256 * i];
    bd[tid] = BD[tid];
    __syncthreads();

    int k = tid >> 4, j = tid & 15;
    #pragma unroll
    for (int n = 0; n < 16; ++n) {
        float acc = 0.f;
        #pragma unroll
        for (int m = 0; m < 16; ++m)
            acc += bd[n * 16 + m] * bw[(n * 16 + m) * 16 + k] * bw[(m * 16 + n) * 16 + j];
        M[tid][n] = acc;
    }
    __syncthreads();

    for (int idx = tid; idx < 512; idx += 256) {
        int s = idx >> 6, lane = idx & 63;
        int q = lane >> 4, n = lane & 15;
        unsigned hw[4], lw[4];
        #pragma unroll
        for (int w = 0; w < 4; ++w) {
            int kk0 = s * 32 + q * 8 + 2 * w;
            float v0 = M[kk0][n], v1 = M[kk0 + 1][n];
            unsigned b0 = __float_as_uint(v0), b1 = __float_as_uint(v1);
            float h0 = __uint_as_float(b0 & 0xFFFF0000u);
            float h1 = __uint_as_float(b1 & 0xFFFF0000u);
            hw[w] = pack_hi16(b0, b1);
            lw[w] = pack_hi16(__float_as_uint(v0 - h0), __float_as_uint(v1 - h1));
        }
        uint4* bh4 = (uint4*)Bhi;
        uint4* bl4 = (uint4*)Blo;
        bh4[idx] = make_uint4(hw[0], hw[1], hw[2], hw[3]);
        bl4[idx] = make_uint4(lw[0], lw[1], lw[2], lw[3]);
    }

    if (tid < 16) {
        float a = bc1[tid];
        #pragma unroll
        for (int n = 0; n < 16; ++n) a += Wc1[tid * 16 + n] * Boff[n];
        bc1p[tid] = a;
    }
}

// ---------------------------------------------------------------------------
// Per-gene MLP table  T[g] = W3*relu(W2*relu(W1*emb[g]+b1)+b2)+b3  (f32)
// ---------------------------------------------------------------------------
__global__ void gene_mlp_kernel(const float* __restrict__ emb,
                                const float* __restrict__ W1, const float* __restrict__ b1,
                                const float* __restrict__ W2, const float* __restrict__ b2,
                                const float* __restrict__ W3, const float* __restrict__ b3,
                                float* __restrict__ T) {
    int g = blockIdx.x * blockDim.x + threadIdx.x;
    if (g >= NG) return;

    float h[D], t[D];
    const float4* ep = (const float4*)(emb + (size_t)g * D);
    float4 v0 = ep[0], v1 = ep[1], v2 = ep[2], v3 = ep[3];
    h[0]=v0.x; h[1]=v0.y; h[2]=v0.z; h[3]=v0.w;
    h[4]=v1.x; h[5]=v1.y; h[6]=v1.z; h[7]=v1.w;
    h[8]=v2.x; h[9]=v2.y; h[10]=v2.z; h[11]=v2.w;
    h[12]=v3.x; h[13]=v3.y; h[14]=v3.z; h[15]=v3.w;

    #pragma unroll
    for (int i = 0; i < D; ++i) {
        float a = b1[i];
        #pragma unroll
        for (int d = 0; d < D; ++d) a = fmaf(W1[i * D + d], h[d], a);
        t[i] = fmaxf(a, 0.f);
    }
    #pragma unroll
    for (int i = 0; i < D; ++i) {
        float a = b2[i];
        #pragma unroll
        for (int d = 0; d < D; ++d) a = fmaf(W2[i * D + d], t[d], a);
        h[i] = fmaxf(a, 0.f);
    }
    #pragma unroll
    for (int i = 0; i < D; ++i) {
        float a = b3[i];
        #pragma unroll
        for (int d = 0; d < D; ++d) a = fmaf(W3[i * D + d], h[d], a);
        t[i] = a;
    }

    float4* tp = (float4*)(T + (size_t)g * D);
    tp[0] = make_float4(t[0], t[1], t[2], t[3]);
    tp[1] = make_float4(t[4], t[5], t[6], t[7]);
    tp[2] = make_float4(t[8], t[9], t[10], t[11]);
    tp[3] = make_float4(t[12], t[13], t[14], t[15]);
}

// ---------------------------------------------------------------------------
// Main kernel: per wave, 64 rows = 4 MFMA tiles of 16 rows.
//   A[m][kk] = e0[m][kk>>4] * e1[m][kk&15]  (built on the fly, bf16 hi/lo split)
//   z = A @ Mmat  via 8 K-slices x 3 MFMAs (hi*hi + hi*lo + lo*hi)
//   head per-lane after LDS transpose roundtrip.
// ---------------------------------------------------------------------------
__global__ void __launch_bounds__(256, 2)
main_kernel(const int* __restrict__ x, const float* __restrict__ phenos,
            const float* __restrict__ T,
            const short* __restrict__ Bhi, const short* __restrict__ Blo,
            const float* __restrict__ bc1p, const float* __restrict__ Wc1,
            const float* __restrict__ Wc2, const float* __restrict__ bc2,
            float* __restrict__ out) {
    int tid  = threadIdx.x;
    int wave = tid >> 6, lane = tid & 63;
    int quad = lane >> 4, nl = lane & 15;
    long base = (long)blockIdx.x * 256 + wave * 64;

    // resident B fragments (hi/lo), one dwordx4 each
    bf16x8 bh[8], bl[8];
    #pragma unroll
    for (int s = 0; s < 8; ++s) {
        bh[s] = ((const bf16x8*)Bhi)[s * 64 + lane];
        bl[s] = ((const bf16x8*)Blo)[s * 64 + lane];
    }

    f32x4 acc[4];
    #pragma unroll
    for (int t = 0; t < 4; ++t) acc[t] = (f32x4){0.f, 0.f, 0.f, 0.f};

    const int c_add = quad >> 1;        // e0 parity select
    const int e1off = (quad & 1) * 8;   // which half of e1 this quad consumes

    #pragma unroll
    for (int t = 0; t < 4; ++t) {
        long r = base + t * 16 + nl;    // this lane's A-row for tile t
        int2 g = ((const int2*)x)[r];

        // e0: full 16 (parity-selected below); e1: only the 8 this quad needs
        const f32x4* p0 = (const f32x4*)(T + g.x * 16);
        const f32x4* p1 = (const f32x4*)(T + g.y * 16 + e1off);
        f32x4 a0 = p0[0], a1 = p0[1], a2 = p0[2], a3 = p0[3];
        f32x4 c0 = p1[0], c1 = p1[1];
        float e0[16] = {a0.x,a0.y,a0.z,a0.w, a1.x,a1.y,a1.z,a1.w,
                        a2.x,a2.y,a2.z,a2.w, a3.x,a3.y,a3.z,a3.w};
        float e1v[8] = {c0.x,c0.y,c0.z,c0.w, c1.x,c1.y,c1.z,c1.w};

        // per-slice e0 scalar: e0[2s + c_add] (runtime parity -> cndmask)
        float ev[8];
        #pragma unroll
        for (int s = 0; s < 8; ++s) ev[s] = c_add ? e0[2 * s + 1] : e0[2 * s];

        #pragma unroll
        for (int s = 0; s < 8; ++s) {
            unsigned hb[8];
            float lo[8];
            #pragma unroll
            for (int jj = 0; jj < 8; ++jj) {
                float p = ev[s] * e1v[jj];
                unsigned b = __float_as_uint(p);
                hb[jj] = b;
                lo[jj] = p - __uint_as_float(b & 0xFFFF0000u);
            }
            uint4 aw = make_uint4(pack_hi16(hb[0], hb[1]), pack_hi16(hb[2], hb[3]),
                                  pack_hi16(hb[4], hb[5]), pack_hi16(hb[6], hb[7]));
            uint4 lw = make_uint4(
                pack_hi16(__float_as_uint(lo[0]), __float_as_uint(lo[1])),
                pack_hi16(__float_as_uint(lo[2]), __float_as_uint(lo[3])),
                pack_hi16(__float_as_uint(lo[4]), __float_as_uint(lo[5])),
                pack_hi16(__float_as_uint(lo[6]), __float_as_uint(lo[7])));
            bf16x8 ah = __builtin_bit_cast(bf16x8, aw);
            bf16x8 al = __builtin_bit_cast(bf16x8, lw);
            acc[t] = __builtin_amdgcn_mfma_f32_16x16x32_bf16(ah, bh[s], acc[t], 0, 0, 0);
            acc[t] = __builtin_amdgcn_mfma_f32_16x16x32_bf16(ah, bl[s], acc[t], 0, 0, 0);
            acc[t] = __builtin_amdgcn_mfma_f32_16x16x32_bf16(al, bh[s], acc[t], 0, 0, 0);
        }
    }

    // LDS transpose: z_lds[wave][n][row]  (stride 65 dwords -> 2-way max on reads)
    __shared__ float zbuf[4][16][65];
    #pragma unroll
    for (int t = 0; t < 4; ++t) {
        #pragma unroll
        for (int reg = 0; reg < 4; ++reg)
            zbuf[wave][nl][t * 16 + quad * 4 + reg] = acc[t][reg];
    }
    __syncthreads();

    // head: one row per lane
    float zv[16];
    #pragma unroll
    for (int n = 0; n < 16; ++n) zv[n] = zbuf[wave][n][lane];

    float a2 = bc2[0];
    #pragma unroll
    for (int i = 0; i < 16; ++i) {
        float u = bc1p[i];
        #pragma unroll
        for (int n = 0; n < 16; ++n) u = fmaf(Wc1[i * 16 + n], zv[n], u);
        u = fmaxf(u, 0.f);
        a2 = fmaf(Wc2[i], u, a2);
    }

    long r2 = base + lane;
    float2 ph = ((const float2*)phenos)[r2];
    out[r2] = ph.x + ph.y + a2;
}

// ---------------------------------------------------------------------------
extern "C" void kernel_launch(void* const* d_in, const int* in_sizes, int n_in,
                              void* d_out, int out_size, void* d_ws, size_t ws_size,
                              hipStream_t stream) {
    const int*   x      = (const int*)  d_in[0];
    const float* phenos = (const float*)d_in[1];
    const float* emb    = (const float*)d_in[2];
    const float* W1     = (const float*)d_in[3];
    const float* b1     = (const float*)d_in[4];
    const float* W2     = (const float*)d_in[5];
    const float* b2     = (const float*)d_in[6];
    const float* W3     = (const float*)d_in[7];
    const float* b3     = (const float*)d_in[8];
    const float* BW     = (const float*)d_in[9];
    const float* BD     = (const float*)d_in[10];
    const float* Boff   = (const float*)d_in[11];
    const float* Wc1    = (const float*)d_in[12];
    const float* bc1    = (const float*)d_in[13];
    const float* Wc2    = (const float*)d_in[14];
    const float* bc2    = (const float*)d_in[15];
    float* out = (float*)d_out;

    // ws layout (bytes): Bhi[0,8192) | Blo[8192,16384) | bc1p[16384,16448) | T[16448, +1.28MB)
    char* wsb = (char*)d_ws;
    short* Bhi = (short*)(wsb);
    short* Blo = (short*)(wsb + 8192);
    float* bc1p = (float*)(wsb + 16384);
    float* T    = (float*)(wsb + 16448);

    build_kernel<<<1, 256, 0, stream>>>(BW, BD, Wc1, bc1, Boff, Bhi, Blo, bc1p);
    gene_mlp_kernel<<<(NG + 255) / 256, 256, 0, stream>>>(emb, W1, b1, W2, b2, W3, b3, T);
    main_kernel<<<NB / 256, 256, 0, stream>>>(x, phenos, T, Bhi, Blo, bc1p, Wc1, Wc2, bc2, out);
}

// Round 3
// 112.805 us; speedup vs baseline: 1.3263x; 1.1235x over previous
//
#include <hip/hip_runtime.h>

#define D  16
#define NB 262144
#define NG 20000
#define ROWPITCH 36   // dwords per staged row (32 data + 4 pad, keeps 16B align)

typedef __attribute__((ext_vector_type(8))) short bf16x8;
typedef __attribute__((ext_vector_type(4))) float f32x4;
typedef __attribute__((ext_vector_type(2))) float f32x2;
typedef __attribute__((ext_vector_type(2))) unsigned u32x2;

// pack the high 16 bits (bf16-truncation) of two f32s into one dword:
// low half = hi16(b0), high half = hi16(b1)
__device__ __forceinline__ unsigned pack_hi16(unsigned b0, unsigned b1) {
    return __builtin_amdgcn_perm(b1, b0, 0x07060302u);
}

// ---------------------------------------------------------------------------
// Prep kernel, 80 blocks:
//   blocks 0..78 : per-gene MLP table T[g] (one thread per gene)
//   block  79    : build M[n,k,j] = sum_m BD[n,m]*BW[n,m,k]*BW[m,n,j],
//                  repack to bf16 hi/lo MFMA B-fragments, fold Boff into bc1.
// ---------------------------------------------------------------------------
__global__ void __launch_bounds__(256)
prep_kernel(const float* __restrict__ emb,
            const float* __restrict__ W1, const float* __restrict__ b1,
            const float* __restrict__ W2, const float* __restrict__ b2,
            const float* __restrict__ W3, const float* __restrict__ b3,
            const float* __restrict__ BW, const float* __restrict__ BD,
            const float* __restrict__ Wc1, const float* __restrict__ bc1,
            const float* __restrict__ Boff,
            float* __restrict__ T, short* __restrict__ Bhi, short* __restrict__ Blo,
            float* __restrict__ bc1p) {
    __shared__ float smem[8704];   // bw[0,4096) | bd[4096,4352) | Mm[4352,8704) pitch 17
    int tid = threadIdx.x;
    int blk = blockIdx.x;

    if (blk < 79) {
        // ---- gene MLP ----
        int g = blk * 256 + tid;
        if (g >= NG) return;
        float h[D], t[D];
        const float4* ep = (const float4*)(emb + (size_t)g * D);
        float4 v0 = ep[0], v1 = ep[1], v2 = ep[2], v3 = ep[3];
        h[0]=v0.x; h[1]=v0.y; h[2]=v0.z; h[3]=v0.w;
        h[4]=v1.x; h[5]=v1.y; h[6]=v1.z; h[7]=v1.w;
        h[8]=v2.x; h[9]=v2.y; h[10]=v2.z; h[11]=v2.w;
        h[12]=v3.x; h[13]=v3.y; h[14]=v3.z; h[15]=v3.w;
        #pragma unroll
        for (int i = 0; i < D; ++i) {
            float a = b1[i];
            #pragma unroll
            for (int d = 0; d < D; ++d) a = fmaf(W1[i * D + d], h[d], a);
            t[i] = fmaxf(a, 0.f);
        }
        #pragma unroll
        for (int i = 0; i < D; ++i) {
            float a = b2[i];
            #pragma unroll
            for (int d = 0; d < D; ++d) a = fmaf(W2[i * D + d], t[d], a);
            h[i] = fmaxf(a, 0.f);
        }
        #pragma unroll
        for (int i = 0; i < D; ++i) {
            float a = b3[i];
            #pragma unroll
            for (int d = 0; d < D; ++d) a = fmaf(W3[i * D + d], h[d], a);
            t[i] = a;
        }
        float4* tp = (float4*)(T + (size_t)g * D);
        tp[0] = make_float4(t[0], t[1], t[2], t[3]);
        tp[1] = make_float4(t[4], t[5], t[6], t[7]);
        tp[2] = make_float4(t[8], t[9], t[10], t[11]);
        tp[3] = make_float4(t[12], t[13], t[14], t[15]);
        return;
    }

    // ---- build block ----
    float* bwS = smem;
    float* bdS = smem + 4096;
    float* MmS = smem + 4352;   // [256][17]: Mm[kk][n] at kk*17+n
    #pragma unroll
    for (int i = 0; i < 16; ++i) bwS[tid + 256 * i] = BW[tid + 256 * i];
    bdS[tid] = BD[tid];
    __syncthreads();

    // thread (n,j): acc[k] = M[n][k][j], vectorized over k via b128 LDS reads
    int n = tid >> 4, j = tid & 15;
    float acc[16];
    #pragma unroll
    for (int k = 0; k < 16; ++k) acc[k] = 0.f;
    #pragma unroll
    for (int m = 0; m < 16; ++m) {
        float sw = bdS[n * 16 + m] * bwS[(m * 16 + n) * 16 + j];
        const f32x4* w1 = (const f32x4*)&bwS[(n * 16 + m) * 16];
        #pragma unroll
        for (int q = 0; q < 4; ++q) {
            f32x4 w = w1[q];
            acc[4 * q + 0] = fmaf(sw, w.x, acc[4 * q + 0]);
            acc[4 * q + 1] = fmaf(sw, w.y, acc[4 * q + 1]);
            acc[4 * q + 2] = fmaf(sw, w.z, acc[4 * q + 2]);
            acc[4 * q + 3] = fmaf(sw, w.w, acc[4 * q + 3]);
        }
    }
    #pragma unroll
    for (int k = 0; k < 16; ++k) MmS[(k * 16 + j) * 17 + n] = acc[k];
    __syncthreads();

    // repack to MFMA B fragments (hi/lo), same layout as verified round 2
    for (int idx = tid; idx < 512; idx += 256) {
        int s = idx >> 6, lane = idx & 63;
        int q = lane >> 4, nn = lane & 15;
        unsigned hw[4], lw[4];
        #pragma unroll
        for (int w = 0; w < 4; ++w) {
            int kk0 = s * 32 + q * 8 + 2 * w;
            float v0 = MmS[kk0 * 17 + nn], v1 = MmS[(kk0 + 1) * 17 + nn];
            unsigned b0 = __float_as_uint(v0), b1 = __float_as_uint(v1);
            float h0 = __uint_as_float(b0 & 0xFFFF0000u);
            float h1 = __uint_as_float(b1 & 0xFFFF0000u);
            hw[w] = pack_hi16(b0, b1);
            lw[w] = pack_hi16(__float_as_uint(v0 - h0), __float_as_uint(v1 - h1));
        }
        ((uint4*)Bhi)[idx] = make_uint4(hw[0], hw[1], hw[2], hw[3]);
        ((uint4*)Blo)[idx] = make_uint4(lw[0], lw[1], lw[2], lw[3]);
    }

    if (tid < 16) {
        float a = bc1[tid];
        #pragma unroll
        for (int nn = 0; nn < 16; ++nn) a += Wc1[tid * 16 + nn] * Boff[nn];
        bc1p[tid] = a;
    }
}

// ---------------------------------------------------------------------------
// Main kernel: wave handles 64 rows (4 MFMA tiles).
// Phase 1: each lane gathers ONLY its own row's T data (8 scattered 16B loads)
//          into LDS (pitch 36 dwords).
// Phase 2: tile loop reads e0 (stride-2 ds_read2) / e1 (b128) from LDS, builds
//          bf16 hi/lo A fragments with packed f32x2 math, 3 MFMAs per K-slice.
// Phase 3: LDS transpose (stride 65) + per-lane classifier head.
// ---------------------------------------------------------------------------
__global__ void __launch_bounds__(256)
main_kernel(const int* __restrict__ x, const float* __restrict__ phenos,
            const float* __restrict__ T,
            const short* __restrict__ Bhi, const short* __restrict__ Blo,
            const float* __restrict__ bc1p, const float* __restrict__ Wc1,
            const float* __restrict__ Wc2, const float* __restrict__ bc2,
            float* __restrict__ out) {
    __shared__ float smem[9216];           // 4 waves x 64 rows x 36 dwords
    int tid  = threadIdx.x;
    int wave = tid >> 6, lane = tid & 63;
    int quad = lane >> 4, nl = lane & 15;
    long base = (long)blockIdx.x * 256 + wave * 64;
    float* stg = smem + wave * 2304;

    // resident B fragments (hi/lo)
    bf16x8 bh[8], bl[8];
    #pragma unroll
    for (int s = 0; s < 8; ++s) {
        bh[s] = ((const bf16x8*)Bhi)[s * 64 + lane];
        bl[s] = ((const bf16x8*)Blo)[s * 64 + lane];
    }

    // ---- phase 1: stage own row (no redundancy) ----
    long r = base + lane;
    int2 g = ((const int2*)x)[r];
    {
        const f32x4* p0 = (const f32x4*)(T + g.x * 16);
        const f32x4* p1 = (const f32x4*)(T + g.y * 16);
        f32x4 c0 = p0[0], c1 = p0[1], c2 = p0[2], c3 = p0[3];
        f32x4 c4 = p1[0], c5 = p1[1], c6 = p1[2], c7 = p1[3];
        f32x4* wp = (f32x4*)(stg + lane * ROWPITCH);
        wp[0] = c0; wp[1] = c1; wp[2] = c2; wp[3] = c3;
        wp[4] = c4; wp[5] = c5; wp[6] = c6; wp[7] = c7;
    }
    __syncthreads();

    // ---- phase 2: MFMA tile loop ----
    f32x4 acc[4];
    #pragma unroll
    for (int t = 0; t < 4; ++t) acc[t] = (f32x4){0.f, 0.f, 0.f, 0.f};
    const int par = quad >> 1;          // e0 parity for this quad
    const int eo  = (quad & 1) * 8;     // e1 half for this quad

    #pragma unroll
    for (int t = 0; t < 4; ++t) {
        const float* rowp = stg + (t * 16 + nl) * ROWPITCH;
        float ev[8];
        #pragma unroll
        for (int s = 0; s < 8; ++s) ev[s] = rowp[2 * s + par];
        f32x4 e1a = *(const f32x4*)(rowp + 16 + eo);
        f32x4 e1b = *(const f32x4*)(rowp + 20 + eo);
        f32x2 e1p[4] = {(f32x2){e1a.x, e1a.y}, (f32x2){e1a.z, e1a.w},
                        (f32x2){e1b.x, e1b.y}, (f32x2){e1b.z, e1b.w}};

        #pragma unroll
        for (int s = 0; s < 8; ++s) {
            f32x2 evv = (f32x2){ev[s], ev[s]};
            unsigned aw[4], lw[4];
            #pragma unroll
            for (int w = 0; w < 4; ++w) {
                f32x2 p  = evv * e1p[w];                       // v_pk_mul_f32
                u32x2 pb = __builtin_bit_cast(u32x2, p);
                u32x2 hb = pb & (u32x2){0xFFFF0000u, 0xFFFF0000u};
                f32x2 lo = p - __builtin_bit_cast(f32x2, hb);  // v_pk_add_f32
                u32x2 lb = __builtin_bit_cast(u32x2, lo);
                aw[w] = pack_hi16(pb.x, pb.y);
                lw[w] = pack_hi16(lb.x, lb.y);
            }
            bf16x8 ah = __builtin_bit_cast(bf16x8, make_uint4(aw[0], aw[1], aw[2], aw[3]));
            bf16x8 al = __builtin_bit_cast(bf16x8, make_uint4(lw[0], lw[1], lw[2], lw[3]));
            acc[t] = __builtin_amdgcn_mfma_f32_16x16x32_bf16(ah, bh[s], acc[t], 0, 0, 0);
            acc[t] = __builtin_amdgcn_mfma_f32_16x16x32_bf16(ah, bl[s], acc[t], 0, 0, 0);
            acc[t] = __builtin_amdgcn_mfma_f32_16x16x32_bf16(al, bh[s], acc[t], 0, 0, 0);
        }
    }

    // ---- phase 3: transpose + head ----
    __syncthreads();                     // staging region reads complete
    float* zb = smem + wave * 1040;      // [16][65]
    #pragma unroll
    for (int t = 0; t < 4; ++t) {
        #pragma unroll
        for (int reg = 0; reg < 4; ++reg)
            zb[nl * 65 + t * 16 + quad * 4 + reg] = acc[t][reg];
    }
    __syncthreads();

    float zv[16];
    #pragma unroll
    for (int n = 0; n < 16; ++n) zv[n] = zb[n * 65 + lane];

    float a2 = bc2[0];
    #pragma unroll
    for (int i = 0; i < 16; ++i) {
        float u = bc1p[i];
        #pragma unroll
        for (int n = 0; n < 16; ++n) u = fmaf(Wc1[i * 16 + n], zv[n], u);
        u = fmaxf(u, 0.f);
        a2 = fmaf(Wc2[i], u, a2);
    }

    float2 ph = ((const float2*)phenos)[r];
    out[r] = ph.x + ph.y + a2;
}

// ---------------------------------------------------------------------------
extern "C" void kernel_launch(void* const* d_in, const int* in_sizes, int n_in,
                              void* d_out, int out_size, void* d_ws, size_t ws_size,
                              hipStream_t stream) {
    const int*   x      = (const int*)  d_in[0];
    const float* phenos = (const float*)d_in[1];
    const float* emb    = (const float*)d_in[2];
    const float* W1     = (const float*)d_in[3];
    const float* b1     = (const float*)d_in[4];
    const float* W2     = (const float*)d_in[5];
    const float* b2     = (const float*)d_in[6];
    const float* W3     = (const float*)d_in[7];
    const float* b3     = (const float*)d_in[8];
    const float* BW     = (const float*)d_in[9];
    const float* BD     = (const float*)d_in[10];
    const float* Boff   = (const float*)d_in[11];
    const float* Wc1    = (const float*)d_in[12];
    const float* bc1    = (const float*)d_in[13];
    const float* Wc2    = (const float*)d_in[14];
    const float* bc2    = (const float*)d_in[15];
    float* out = (float*)d_out;

    // ws layout (bytes): Bhi[0,8192) | Blo[8192,16384) | bc1p[16384,16448) | T[16448,+1.28MB)
    char* wsb = (char*)d_ws;
    short* Bhi  = (short*)(wsb);
    short* Blo  = (short*)(wsb + 8192);
    float* bc1p = (float*)(wsb + 16384);
    float* T    = (float*)(wsb + 16448);

    prep_kernel<<<80, 256, 0, stream>>>(emb, W1, b1, W2, b2, W3, b3, BW, BD,
                                        Wc1, bc1, Boff, T, Bhi, Blo, bc1p);
    main_kernel<<<NB / 256, 256, 0, stream>>>(x, phenos, T, Bhi, Blo, bc1p, Wc1, Wc2, bc2, out);
}

// Round 4
// 105.752 us; speedup vs baseline: 1.4147x; 1.0667x over previous
//
#include <hip/hip_runtime.h>
#include <hip/hip_bf16.h>

#define D  16
#define NB 262144
#define NG 20000
#define ROWPITCH 36   // dwords per staged row (32 data + 4 pad, keeps 16B align)
#define ZPITCH   20   // dwords per z row in transpose buffer (16 data + 4 pad)

typedef __attribute__((ext_vector_type(8))) short bf16x8;
typedef __attribute__((ext_vector_type(4))) float f32x4;
typedef __attribute__((ext_vector_type(2))) float f32x2;

// pack the high 16 bits (bf16-truncation) of two f32s into one dword:
// low half = hi16(b0), high half = hi16(b1)
__device__ __forceinline__ unsigned pack_hi16(unsigned b0, unsigned b1) {
    return __builtin_amdgcn_perm(b1, b0, 0x07060302u);
}

// ---------------------------------------------------------------------------
// Prep kernel, 80 blocks:
//   blocks 0..78 : per-gene MLP table T[g] (one thread per gene)
//   block  79    : build M[n,k,j] = sum_m BD[n,m]*BW[n,m,k]*BW[m,n,j],
//                  repack to bf16 hi/lo MFMA B-fragments, fold Boff into bc1.
// ---------------------------------------------------------------------------
__global__ void __launch_bounds__(256)
prep_kernel(const float* __restrict__ emb,
            const float* __restrict__ W1, const float* __restrict__ b1,
            const float* __restrict__ W2, const float* __restrict__ b2,
            const float* __restrict__ W3, const float* __restrict__ b3,
            const float* __restrict__ BW, const float* __restrict__ BD,
            const float* __restrict__ Wc1, const float* __restrict__ bc1,
            const float* __restrict__ Boff,
            float* __restrict__ T, short* __restrict__ Bhi, short* __restrict__ Blo,
            float* __restrict__ bc1p) {
    __shared__ float smem[8704];   // bw[0,4096) | bd[4096,4352) | Mm[4352,8704) pitch 17
    int tid = threadIdx.x;
    int blk = blockIdx.x;

    if (blk < 79) {
        // ---- gene MLP ----
        int g = blk * 256 + tid;
        if (g >= NG) return;
        float h[D], t[D];
        const float4* ep = (const float4*)(emb + (size_t)g * D);
        float4 v0 = ep[0], v1 = ep[1], v2 = ep[2], v3 = ep[3];
        h[0]=v0.x; h[1]=v0.y; h[2]=v0.z; h[3]=v0.w;
        h[4]=v1.x; h[5]=v1.y; h[6]=v1.z; h[7]=v1.w;
        h[8]=v2.x; h[9]=v2.y; h[10]=v2.z; h[11]=v2.w;
        h[12]=v3.x; h[13]=v3.y; h[14]=v3.z; h[15]=v3.w;
        #pragma unroll
        for (int i = 0; i < D; ++i) {
            float a = b1[i];
            #pragma unroll
            for (int d = 0; d < D; ++d) a = fmaf(W1[i * D + d], h[d], a);
            t[i] = fmaxf(a, 0.f);
        }
        #pragma unroll
        for (int i = 0; i < D; ++i) {
            float a = b2[i];
            #pragma unroll
            for (int d = 0; d < D; ++d) a = fmaf(W2[i * D + d], t[d], a);
            h[i] = fmaxf(a, 0.f);
        }
        #pragma unroll
        for (int i = 0; i < D; ++i) {
            float a = b3[i];
            #pragma unroll
            for (int d = 0; d < D; ++d) a = fmaf(W3[i * D + d], h[d], a);
            t[i] = a;
        }
        float4* tp = (float4*)(T + (size_t)g * D);
        tp[0] = make_float4(t[0], t[1], t[2], t[3]);
        tp[1] = make_float4(t[4], t[5], t[6], t[7]);
        tp[2] = make_float4(t[8], t[9], t[10], t[11]);
        tp[3] = make_float4(t[12], t[13], t[14], t[15]);
        return;
    }

    // ---- build block ----
    float* bwS = smem;
    float* bdS = smem + 4096;
    float* MmS = smem + 4352;   // [256][17]: Mm[kk][n] at kk*17+n
    #pragma unroll
    for (int i = 0; i < 16; ++i) bwS[tid + 256 * i] = BW[tid + 256 * i];
    bdS[tid] = BD[tid];
    __syncthreads();

    // thread (n,j): acc[k] = M[n][k][j], vectorized over k via b128 LDS reads
    int n = tid >> 4, j = tid & 15;
    float acc[16];
    #pragma unroll
    for (int k = 0; k < 16; ++k) acc[k] = 0.f;
    #pragma unroll
    for (int m = 0; m < 16; ++m) {
        float sw = bdS[n * 16 + m] * bwS[(m * 16 + n) * 16 + j];
        const f32x4* w1 = (const f32x4*)&bwS[(n * 16 + m) * 16];
        #pragma unroll
        for (int q = 0; q < 4; ++q) {
            f32x4 w = w1[q];
            acc[4 * q + 0] = fmaf(sw, w.x, acc[4 * q + 0]);
            acc[4 * q + 1] = fmaf(sw, w.y, acc[4 * q + 1]);
            acc[4 * q + 2] = fmaf(sw, w.z, acc[4 * q + 2]);
            acc[4 * q + 3] = fmaf(sw, w.w, acc[4 * q + 3]);
        }
    }
    #pragma unroll
    for (int k = 0; k < 16; ++k) MmS[(k * 16 + j) * 17 + n] = acc[k];
    __syncthreads();

    // repack to MFMA B fragments (hi/lo), same layout as verified round 2/3
    for (int idx = tid; idx < 512; idx += 256) {
        int s = idx >> 6, lane = idx & 63;
        int q = lane >> 4, nn = lane & 15;
        unsigned hw[4], lw[4];
        #pragma unroll
        for (int w = 0; w < 4; ++w) {
            int kk0 = s * 32 + q * 8 + 2 * w;
            float v0 = MmS[kk0 * 17 + nn], v1 = MmS[(kk0 + 1) * 17 + nn];
            unsigned b0 = __float_as_uint(v0), b1 = __float_as_uint(v1);
            float h0 = __uint_as_float(b0 & 0xFFFF0000u);
            float h1 = __uint_as_float(b1 & 0xFFFF0000u);
            hw[w] = pack_hi16(b0, b1);
            lw[w] = pack_hi16(__float_as_uint(v0 - h0), __float_as_uint(v1 - h1));
        }
        ((uint4*)Bhi)[idx] = make_uint4(hw[0], hw[1], hw[2], hw[3]);
        ((uint4*)Blo)[idx] = make_uint4(lw[0], lw[1], lw[2], lw[3]);
    }

    if (tid < 16) {
        float a = bc1[tid];
        #pragma unroll
        for (int nn = 0; nn < 16; ++nn) a += Wc1[tid * 16 + nn] * Boff[nn];
        bc1p[tid] = a;
    }
}

// ---------------------------------------------------------------------------
// Main kernel: wave handles 64 rows (4 MFMA tiles).
// Phase 1: each lane gathers its own row's T data into LDS (pitch 36).
// Phase 2: A fragment = RNE-bf16(e0*e1) via v_cvt_pk_bf16_f32;
//          2 MFMAs per K-slice: ah*Bhi + ah*Blo  (B carries 16-bit precision).
// Phase 3: LDS transpose (pitch 20, b128 reads) + pk-vectorized head.
// ---------------------------------------------------------------------------
__global__ void __launch_bounds__(256)
main_kernel(const int* __restrict__ x, const float* __restrict__ phenos,
            const float* __restrict__ T,
            const short* __restrict__ Bhi, const short* __restrict__ Blo,
            const float* __restrict__ bc1p, const float* __restrict__ Wc1,
            const float* __restrict__ Wc2, const float* __restrict__ bc2,
            float* __restrict__ out) {
    __shared__ float smem[9216];           // stg: 4 waves x 64 rows x 36 dwords
    int tid  = threadIdx.x;                // zb (aliased): 4 waves x 64 x 20
    int wave = tid >> 6, lane = tid & 63;
    int quad = lane >> 4, nl = lane & 15;
    long base = (long)blockIdx.x * 256 + wave * 64;
    float* stg = smem + wave * 2304;

    // resident B fragments (hi/lo)
    bf16x8 bh[8], bl[8];
    #pragma unroll
    for (int s = 0; s < 8; ++s) {
        bh[s] = ((const bf16x8*)Bhi)[s * 64 + lane];
        bl[s] = ((const bf16x8*)Blo)[s * 64 + lane];
    }

    // ---- phase 1: stage own row ----
    long r = base + lane;
    int2 g = ((const int2*)x)[r];
    {
        const f32x4* p0 = (const f32x4*)(T + g.x * 16);
        const f32x4* p1 = (const f32x4*)(T + g.y * 16);
        f32x4 c0 = p0[0], c1 = p0[1], c2 = p0[2], c3 = p0[3];
        f32x4 c4 = p1[0], c5 = p1[1], c6 = p1[2], c7 = p1[3];
        f32x4* wp = (f32x4*)(stg + lane * ROWPITCH);
        wp[0] = c0; wp[1] = c1; wp[2] = c2; wp[3] = c3;
        wp[4] = c4; wp[5] = c5; wp[6] = c6; wp[7] = c7;
    }
    __syncthreads();

    // ---- phase 2: MFMA tile loop ----
    f32x4 acc[4];
    #pragma unroll
    for (int t = 0; t < 4; ++t) acc[t] = (f32x4){0.f, 0.f, 0.f, 0.f};
    const int par = quad >> 1;          // e0 parity for this quad
    const int eo  = (quad & 1) * 8;     // e1 half for this quad

    #pragma unroll
    for (int t = 0; t < 4; ++t) {
        const float* rowp = stg + (t * 16 + nl) * ROWPITCH;
        float ev[8];
        #pragma unroll
        for (int s = 0; s < 8; ++s) ev[s] = rowp[2 * s + par];
        f32x4 e1a = *(const f32x4*)(rowp + 16 + eo);
        f32x4 e1b = *(const f32x4*)(rowp + 20 + eo);
        float2 e1p[4] = {make_float2(e1a.x, e1a.y), make_float2(e1a.z, e1a.w),
                         make_float2(e1b.x, e1b.y), make_float2(e1b.z, e1b.w)};

        #pragma unroll
        for (int s = 0; s < 8; ++s) {
            unsigned aw[4];
            #pragma unroll
            for (int w = 0; w < 4; ++w) {
                float2 p = make_float2(ev[s] * e1p[w].x, ev[s] * e1p[w].y); // v_pk_mul_f32
                __hip_bfloat162 hv = __float22bfloat162_rn(p);              // v_cvt_pk_bf16_f32
                aw[w] = *(unsigned*)&hv;
            }
            bf16x8 ah = __builtin_bit_cast(bf16x8, make_uint4(aw[0], aw[1], aw[2], aw[3]));
            acc[t] = __builtin_amdgcn_mfma_f32_16x16x32_bf16(ah, bh[s], acc[t], 0, 0, 0);
            acc[t] = __builtin_amdgcn_mfma_f32_16x16x32_bf16(ah, bl[s], acc[t], 0, 0, 0);
        }
    }

    // ---- phase 3: transpose + head ----
    __syncthreads();                     // all waves done reading stg (zb aliases it)
    float* zb = smem + wave * 1280;      // [64][ZPITCH]
    #pragma unroll
    for (int t = 0; t < 4; ++t) {
        #pragma unroll
        for (int reg = 0; reg < 4; ++reg)
            zb[(t * 16 + quad * 4 + reg) * ZPITCH + nl] = acc[t][reg];
    }
    __syncthreads();

    // head: one row per lane; z read as 4 x b128, math in packed f32x2
    const float* zr = zb + lane * ZPITCH;
    f32x4 q0 = *(const f32x4*)(zr + 0);
    f32x4 q1 = *(const f32x4*)(zr + 4);
    f32x4 q2 = *(const f32x4*)(zr + 8);
    f32x4 q3 = *(const f32x4*)(zr + 12);
    f32x2 zv2[8] = {(f32x2){q0.x, q0.y}, (f32x2){q0.z, q0.w},
                    (f32x2){q1.x, q1.y}, (f32x2){q1.z, q1.w},
                    (f32x2){q2.x, q2.y}, (f32x2){q2.z, q2.w},
                    (f32x2){q3.x, q3.y}, (f32x2){q3.z, q3.w}};

    const f32x2* w2 = (const f32x2*)Wc1;   // Wc1 rows are 16 floats, 8B aligned
    float a2 = bc2[0];
    #pragma unroll
    for (int i = 0; i < 16; ++i) {
        f32x2 u2 = (f32x2){0.f, 0.f};
        #pragma unroll
        for (int n2 = 0; n2 < 8; ++n2) u2 += w2[i * 8 + n2] * zv2[n2];  // v_pk_fma_f32
        float u = u2.x + u2.y + bc1p[i];
        u = fmaxf(u, 0.f);
        a2 = fmaf(Wc2[i], u, a2);
    }

    float2 ph = ((const float2*)phenos)[r];
    out[r] = ph.x + ph.y + a2;
}

// ---------------------------------------------------------------------------
extern "C" void kernel_launch(void* const* d_in, const int* in_sizes, int n_in,
                              void* d_out, int out_size, void* d_ws, size_t ws_size,
                              hipStream_t stream) {
    const int*   x      = (const int*)  d_in[0];
    const float* phenos = (const float*)d_in[1];
    const float* emb    = (const float*)d_in[2];
    const float* W1     = (const float*)d_in[3];
    const float* b1     = (const float*)d_in[4];
    const float* W2     = (const float*)d_in[5];
    const float* b2     = (const float*)d_in[6];
    const float* W3     = (const float*)d_in[7];
    const float* b3     = (const float*)d_in[8];
    const float* BW     = (const float*)d_in[9];
    const float* BD     = (const float*)d_in[10];
    const float* Boff   = (const float*)d_in[11];
    const float* Wc1    = (const float*)d_in[12];
    const float* bc1    = (const float*)d_in[13];
    const float* Wc2    = (const float*)d_in[14];
    const float* bc2    = (const float*)d_in[15];
    float* out = (float*)d_out;

    // ws layout (bytes): Bhi[0,8192) | Blo[8192,16384) | bc1p[16384,16448) | T[16448,+1.28MB)
    char* wsb = (char*)d_ws;
    short* Bhi  = (short*)(wsb);
    short* Blo  = (short*)(wsb + 8192);
    float* bc1p = (float*)(wsb + 16384);
    float* T    = (float*)(wsb + 16448);

    prep_kernel<<<80, 256, 0, stream>>>(emb, W1, b1, W2, b2, W3, b3, BW, BD,
                                        Wc1, bc1, Boff, T, Bhi, Blo, bc1p);
    main_kernel<<<NB / 256, 256, 0, stream>>>(x, phenos, T, Bhi, Blo, bc1p, Wc1, Wc2, bc2, out);
}